// Round 6
// baseline (227.237 us; speedup 1.0000x reference)
//
#include <hip/hip_runtime.h>

// Problem constants (B=16, D=128, H=32, W=32, K=8192)
#define D 128
#define HW 1024
#define NROWS 16384
#define K 8192

// d_out layout (float offsets): z_q_st | indices | new_codebook | new_count | new_weight
#define OUT0 0
#define OUT1 2097152
#define OUT2 2113536
#define OUT3 3162112
#define OUT4 3170304

typedef __attribute__((ext_vector_type(8))) _Float16 half8;
typedef __attribute__((ext_vector_type(16))) float f32x16;
typedef unsigned short u16;
typedef unsigned long long u64;

// ---- async global->LDS, 16B per lane (dst = wave-uniform base + lane*16) ----
__device__ __forceinline__ void gld16(const u16* gsrc, u16* ldst) {
    __builtin_amdgcn_global_load_lds(
        (const __attribute__((address_space(1))) unsigned int*)gsrc,
        (__attribute__((address_space(3))) unsigned int*)ldst,
        16, 0, 0);
}

// ---- cb prep: fp16 hi/lo split (sub-unit layout) + cnorm + dw-zero + inits ----
// B layout: sub-unit s = g*2+khalf (g=64-col group, khalf=64-dim half), 16 KiB each:
//   [s(256)][ Bh: [kq(8)][col(64)][j(8)] | Bl: same ]   (kq = ks*2+kh, dims khalf*64+kq*8+j)
__global__ __launch_bounds__(256) void k_prep_cb(const float* __restrict__ cb,
                                                 u16* __restrict__ Bg,
                                                 float* __restrict__ cnorm,
                                                 u64* __restrict__ packed,
                                                 float* __restrict__ counts,
                                                 float* __restrict__ dw) {
    const int tid = threadIdx.x;
    int kk = tid & 15;
    int k = blockIdx.x * 16 + (tid >> 4);
    const float* src = cb + (size_t)k * D + kk * 8;
    half8 h, l;
    float s = 0.f;
#pragma unroll
    for (int j = 0; j < 8; ++j) {
        float v = src[j];
        s += v * v;
        _Float16 hv = (_Float16)v;              // RN f32->f16
        _Float16 lv = (_Float16)(v - (float)hv);
        h[j] = hv;
        l[j] = lv;
    }
    int g = k >> 6, col = k & 63, khalf = kk >> 3, kq = kk & 7;
    size_t base = ((size_t)(g * 2 + khalf)) * 8192 + ((size_t)kq * 64 + col) * 8;
    *(half8*)((_Float16*)Bg + base) = h;            // Bh plane
    *(half8*)((_Float16*)Bg + base + 4096) = l;     // Bl plane
#pragma unroll
    for (int off = 8; off > 0; off >>= 1) s += __shfl_down(s, off);
    if (kk == 0) cnorm[k] = s;
    // zero dw: 512 blocks x 256 thr x 8 floats = K*D exactly
    float4 z4 = {0.f, 0.f, 0.f, 0.f};
    size_t zi = ((size_t)blockIdx.x * 256 + tid) * 8;
    *(float4*)(dw + zi) = z4;
    *(float4*)(dw + zi + 4) = z4;
    // init packed sentinel (+inf) and counts
    if (blockIdx.x < 64) packed[blockIdx.x * 256 + tid] = ~0ull;
    else if (blockIdx.x < 96) counts[(blockIdx.x - 64) * 256 + tid] = 0.f;
}

// ---- main: in-kernel A-split + 3-pass fp16-split GEMM + fused argmin ----
// grid: 256 rowgroups (64 rows) x 4 ksplits (2048 cols) = 1024 blocks.
// block: 256 thr = 4 waves (2 wy x 2 wx) -> 64 rows x 64 cols per sub-unit.
// B staged in 16 KiB sub-units (64 cols x 64 dims, Bh+Bl), 2x16 KiB LDS dbuf
// -> 4 blocks/CU; prefetch stays in flight across raw s_barrier via vmcnt(4).
__global__ __launch_bounds__(256, 4) void k_argmin_mfma(
        const float* __restrict__ z_e,
        const u16* __restrict__ Bg,
        const float* __restrict__ cnorm, u64* __restrict__ packed) {
    __shared__ u16 lds[2][8192];                // 2 x 16 KiB

    const int tid = threadIdx.x;
    const int ln  = tid & 63;
    const int l31 = ln & 31;
    const int lh  = ln >> 5;                    // k-half select within frag
    const int wy  = (tid >> 6) & 1;             // row band 0..1
    const int wx  = tid >> 7;                   // col half 0..1

    const int rg = blockIdx.x >> 2;             // 256 rowgroups x 64 rows
    const int k0 = (blockIdx.x & 3) * 2048;     // col split
    const int s0 = (k0 >> 6) * 2;               // first global sub-unit

    // ---- load & fp16-split this wave's A rows (32 rows x 128 d) from z_e ----
    // A frag (mfma 32x32x16): lane(l31=row, lh) supplies k = lh*8+j of chunk ks
    const int rowA = rg * 64 + wy * 32 + l31;
    const float* za = z_e + (size_t)(rowA >> 10) * (D * HW) + (rowA & 1023);
    half8 Ah[8], Al[8];
#pragma unroll
    for (int ks = 0; ks < 8; ++ks) {
        half8 h, l;
#pragma unroll
        for (int j = 0; j < 8; ++j) {
            float v = za[(size_t)(ks * 16 + lh * 8 + j) * HW];
            _Float16 hv = (_Float16)v;
            _Float16 lv = (_Float16)(v - (float)hv);
            h[j] = hv;
            l[j] = lv;
        }
        Ah[ks] = h;
        Al[ks] = l;
    }

    // ---- stage sub-unit 0 (16 KiB, 4 gld16/thread) ----
    {
        const u16* src = Bg + (size_t)s0 * 8192;
#pragma unroll
        for (int r = 0; r < 4; ++r)
            gld16(src + (r * 256 + tid) * 8, lds[0] + (r * 256 + tid) * 8);
    }

    float minv[16];
    int   mini[16];
#pragma unroll
    for (int r = 0; r < 16; ++r) { minv[r] = INFINITY; mini[r] = 0; }

    const int bo_base = wx * 32 + l31;

#pragma unroll 1
    for (int g = 0; g < 32; ++g) {
        const int colv = k0 + g * 64 + wx * 32 + l31;
        float cn0 = cnorm[colv];
        f32x16 acc = {};
#pragma unroll
        for (int half = 0; half < 2; ++half) {  // two 64-dim sub-units per colgroup
            const int u = g * 2 + half;
            if (u + 1 < 64) {
                const u16* src = Bg + (size_t)(s0 + u + 1) * 8192;
                u16* dst = lds[1 - half];
#pragma unroll
                for (int r = 0; r < 4; ++r)
                    gld16(src + (r * 256 + tid) * 8, dst + (r * 256 + tid) * 8);
                // wait for *this* sub-unit's stage; next one's 4 loads in flight
                asm volatile("s_waitcnt vmcnt(4)" ::: "memory");
            } else {
                asm volatile("s_waitcnt vmcnt(0)" ::: "memory");
            }
            asm volatile("s_barrier" ::: "memory");

            const _Float16* bh = (const _Float16*)lds[half];
#pragma unroll
            for (int ks = 0; ks < 4; ++ks) {
                const int bo = ((ks * 2 + lh) * 64 + bo_base) * 8;
                half8 bl = *(const half8*)(bh + 4096 + bo);
                half8 b0 = *(const half8*)(bh + bo);
                const int ak = half * 4 + ks;
                acc = __builtin_amdgcn_mfma_f32_32x32x16_f16(Ah[ak], bl, acc, 0, 0, 0);
                acc = __builtin_amdgcn_mfma_f32_32x32x16_f16(Ah[ak], b0, acc, 0, 0, 0);
                acc = __builtin_amdgcn_mfma_f32_32x32x16_f16(Al[ak], b0, acc, 0, 0, 0);
            }
            // all waves done reading lds[half] before its next overwrite
            asm volatile("s_barrier" ::: "memory");
        }
        // fold dist = cnorm - 2*dot into running argmin (ascending col order)
#pragma unroll
        for (int r = 0; r < 16; ++r) {
            float d0 = fmaf(-2.0f, acc[r], cn0);
            if (d0 < minv[r]) { minv[r] = d0; mini[r] = colv; }
        }
    }

    // ---- reduce across the 32 l31-lanes sharing each output row ----
#pragma unroll
    for (int r = 0; r < 16; ++r) {
        float v = minv[r];
        int ix = mini[r];
#pragma unroll
        for (int off = 1; off < 32; off <<= 1) {
            float v2 = __shfl_xor(v, off);
            int i2 = __shfl_xor(ix, off);
            if (v2 < v || (v2 == v && i2 < ix)) { v = v2; ix = i2; }
        }
        if (l31 == 0) {
            // C/D row map (m74/m101): row = (reg&3) + 8*(reg>>2) + 4*(lane>>5)
            int row = rg * 64 + wy * 32 + 4 * lh + (r & 3) + 8 * (r >> 2);
            unsigned int uenc = __float_as_uint(v);
            uenc = (uenc & 0x80000000u) ? ~uenc : (uenc | 0x80000000u);  // monotonic
            u64 pk = ((u64)uenc << 13) | (u64)(unsigned)ix;
            atomicMin(&packed[row], pk);
        }
    }
}

// ---- epilogue: indices, z_q_st, counts, dw ----
__global__ __launch_bounds__(256) void k_epilogue(const float* __restrict__ z_e,
                                                  const float* __restrict__ cb,
                                                  const u64* __restrict__ packed,
                                                  float* __restrict__ out0,
                                                  float* __restrict__ out1,
                                                  float* __restrict__ counts,
                                                  float* __restrict__ dw) {
    __shared__ int idxS[64];
    const int tid = threadIdx.x;
    const int n0 = blockIdx.x * 64;
    const int bb = n0 >> 10, p0 = n0 & 1023;

    if (tid < 64) {
        int ix = (int)(packed[n0 + tid] & 0x1FFFull);
        idxS[tid] = ix;
        out1[n0 + tid] = (float)ix;
        atomicAdd(&counts[ix], 1.0f);
    }
    __syncthreads();

    const float* zb = z_e + (size_t)bb * (D * HW) + p0;
    float* ob = out0 + (size_t)bb * (D * HW) + p0;

    for (int i = tid; i < 64 * D; i += 256) {
        int d = i >> 6, r = i & 63;
        float z = zb[(size_t)d * HW + r];
        float c = cb[(size_t)idxS[r] * D + d];
        ob[(size_t)d * HW + r] = z + (c - z);
    }
    for (int i = tid; i < 64 * D; i += 256) {
        int r = i >> 7, d = i & 127;
        atomicAdd(&dw[(size_t)idxS[r] * D + d], zb[(size_t)d * HW + r]);
    }
}

__global__ __launch_bounds__(256) void k_final(const float* __restrict__ ema_count,
                                               const float* __restrict__ ema_weight,
                                               float* __restrict__ out2,
                                               float* __restrict__ out3,
                                               float* __restrict__ out4) {
    int gid = blockIdx.x * 256 + threadIdx.x;   // over K*D
    int k = gid >> 7, d = gid & 127;
    float cnt_raw = out3[k];
    float dw_raw = out4[gid];
    __syncthreads();
    float nc = 0.99f * ema_count[k] + 0.01f * cnt_raw;
    float nw = 0.99f * ema_weight[gid] + 0.01f * dw_raw;
    out4[gid] = nw;
    out2[gid] = nw / fmaxf(nc, 1.0f);
    if (d == 0) out3[k] = nc;
}

extern "C" void kernel_launch(void* const* d_in, const int* in_sizes, int n_in,
                              void* d_out, int out_size, void* d_ws, size_t ws_size,
                              hipStream_t stream) {
    const float* z_e        = (const float*)d_in[0];
    const float* cb         = (const float*)d_in[1];
    const float* ema_count  = (const float*)d_in[2];
    const float* ema_weight = (const float*)d_in[3];
    float* out = (float*)d_out;

    float* cnorm = (float*)d_ws;                                   // K floats
    u64* packed = (u64*)((char*)d_ws + K * 4);                     // NROWS u64

    // fp16-split B lives in out2 (4 MB, rewritten by k_final later):
    u16* Bg = (u16*)(out + OUT2);                                  // 256 sub-units x 16 KiB

    k_prep_cb    <<<K / 16,        256, 0, stream>>>(cb, Bg, cnorm, packed,
                                                     out + OUT3, out + OUT4);
    k_argmin_mfma<<<1024,          256, 0, stream>>>(z_e, Bg, cnorm, packed);
    k_epilogue   <<<NROWS / 64,    256, 0, stream>>>(z_e, cb, packed,
                                                     out + OUT0, out + OUT1,
                                                     out + OUT3, out + OUT4);
    k_final      <<<(K * D) / 256, 256, 0, stream>>>(ema_count, ema_weight,
                                                     out + OUT2, out + OUT3, out + OUT4);
}

// Round 7
// 209.725 us; speedup vs baseline: 1.0835x; 1.0835x over previous
//
#include <hip/hip_runtime.h>

// Problem constants (B=16, D=128, H=32, W=32, K=8192)
#define D 128
#define HW 1024
#define NROWS 16384
#define K 8192
#define NU 32   // 64-col units per block (2048-col k-split / 64)

// d_out layout (float offsets): z_q_st | indices | new_codebook | new_count | new_weight
#define OUT0 0
#define OUT1 2097152
#define OUT2 2113536
#define OUT3 3162112
#define OUT4 3170304

typedef __attribute__((ext_vector_type(8))) _Float16 half8;
typedef __attribute__((ext_vector_type(16))) float f32x16;
typedef unsigned short u16;
typedef unsigned long long u64;

// ---- async global->LDS, 16B per lane (dst = wave-uniform base + lane*16) ----
__device__ __forceinline__ void gld16(const u16* gsrc, u16* ldst) {
    __builtin_amdgcn_global_load_lds(
        (const __attribute__((address_space(1))) unsigned int*)gsrc,
        (__attribute__((address_space(3))) unsigned int*)ldst,
        16, 0, 0);
}

// ---- cb prep: fp16 hi/lo split (r5 unit layout) + cnorm + dw-zero + inits ----
// B layout: [unit g(128)][ Bh: [kk(16)][col(64)][j(8)] | Bl: same ] (32 KiB/unit)
__global__ __launch_bounds__(256) void k_prep_cb(const float* __restrict__ cb,
                                                 u16* __restrict__ Bg,
                                                 float* __restrict__ cnorm,
                                                 u64* __restrict__ packed,
                                                 float* __restrict__ counts,
                                                 float* __restrict__ dw) {
    const int tid = threadIdx.x;
    int kk = tid & 15;
    int k = blockIdx.x * 16 + (tid >> 4);
    const float* src = cb + (size_t)k * D + kk * 8;
    half8 h, l;
    float s = 0.f;
#pragma unroll
    for (int j = 0; j < 8; ++j) {
        float v = src[j];
        s += v * v;
        _Float16 hv = (_Float16)v;              // RN f32->f16
        _Float16 lv = (_Float16)(v - (float)hv);
        h[j] = hv;
        l[j] = lv;
    }
    int g = k >> 6, col = k & 63;
    size_t offH = (size_t)g * 16384 + ((size_t)kk * 64 + col) * 8;
    *(half8*)((_Float16*)Bg + offH) = h;
    *(half8*)((_Float16*)Bg + offH + 8192) = l;
#pragma unroll
    for (int off = 8; off > 0; off >>= 1) s += __shfl_down(s, off);
    if (kk == 0) cnorm[k] = s;
    // zero dw: 512 blocks x 256 thr x 8 floats = K*D exactly
    float4 z4 = {0.f, 0.f, 0.f, 0.f};
    size_t zi = ((size_t)blockIdx.x * 256 + tid) * 8;
    *(float4*)(dw + zi) = z4;
    *(float4*)(dw + zi + 4) = z4;
    // init packed sentinel (+inf) and counts
    if (blockIdx.x < 64) packed[blockIdx.x * 256 + tid] = ~0ull;
    else if (blockIdx.x < 96) counts[(blockIdx.x - 64) * 256 + tid] = 0.f;
}

// ---- main: in-kernel A-split + 3-pass fp16-split GEMM + fused argmin ----
// grid: 128 rowgroups (128 rows) x 4 ksplits = 512 blocks; 256 thr = 4 waves
// (wy 0..1 x wx 0..1). Wave tile: 64 rows (2 row-tiles) x 32 cols -> each
// bh/bl LDS fragment feeds 6 MFMAs (LDS floor ~21 us < MFMA floor 41 us).
// B staged in 32 KiB units, 2x32 KiB dbuf (2 blocks/CU); prefetch stays in
// flight across raw s_barrier via vmcnt(8).
__global__ __launch_bounds__(256, 2) void k_argmin_mfma(
        const float* __restrict__ z_e,
        const u16* __restrict__ Bg,
        const float* __restrict__ cnorm, u64* __restrict__ packed) {
    __shared__ u16 lds[2][16384];               // 2 x 32 KiB

    const int tid = threadIdx.x;
    const int ln  = tid & 63;
    const int l31 = ln & 31;
    const int lh  = ln >> 5;                    // k-half select within frag
    const int wy  = (tid >> 6) & 1;             // 64-row band
    const int wx  = tid >> 7;                   // 32-col half

    const int rg = blockIdx.x >> 2;             // 128 rowgroups x 128 rows
    const int k0 = (blockIdx.x & 3) * 2048;     // col split
    const int g0 = k0 >> 6;                     // first 64-col B-unit

    // ---- load & fp16-split A rows for both row-tiles (in-kernel, no prep_z) ----
    // A frag (mfma 32x32x16): lane(l31=row, lh) supplies dim ks*16 + lh*8 + j
    half8 Ah[2][8], Al[2][8];
#pragma unroll
    for (int rt = 0; rt < 2; ++rt) {
        const int rowA = rg * 128 + wy * 64 + rt * 32 + l31;
        const float* za = z_e + (size_t)(rowA >> 10) * (D * HW) + (rowA & 1023);
#pragma unroll
        for (int ks = 0; ks < 8; ++ks) {
            half8 h, l;
#pragma unroll
            for (int j = 0; j < 8; ++j) {
                float v = za[(size_t)(ks * 16 + lh * 8 + j) * HW];
                _Float16 hv = (_Float16)v;
                _Float16 lv = (_Float16)(v - (float)hv);
                h[j] = hv;
                l[j] = lv;
            }
            Ah[rt][ks] = h;
            Al[rt][ks] = l;
        }
    }

    // ---- stage unit 0 (32 KiB, 8 gld16/thread) ----
    {
        const u16* src = Bg + (size_t)g0 * 16384;
#pragma unroll
        for (int r = 0; r < 8; ++r)
            gld16(src + (r * 256 + tid) * 8, lds[0] + (r * 256 + tid) * 8);
    }

    float minv[2][16];
    int   mini[2][16];
#pragma unroll
    for (int rt = 0; rt < 2; ++rt)
#pragma unroll
        for (int r = 0; r < 16; ++r) { minv[rt][r] = INFINITY; mini[rt][r] = 0; }

    const int bo_base = wx * 32 + l31;

#pragma unroll 1
    for (int u = 0; u < NU; ++u) {
        const int colv = k0 + u * 64 + wx * 32 + l31;
        float cn0 = cnorm[colv];

        if (u + 1 < NU) {
            const u16* src = Bg + (size_t)(g0 + u + 1) * 16384;
            u16* dst = lds[(u + 1) & 1];
#pragma unroll
            for (int r = 0; r < 8; ++r)
                gld16(src + (r * 256 + tid) * 8, dst + (r * 256 + tid) * 8);
            // wait for *this* unit's stage; next unit's 8 loads stay in flight
            asm volatile("s_waitcnt vmcnt(8)" ::: "memory");
        } else {
            asm volatile("s_waitcnt vmcnt(0)" ::: "memory");
        }
        asm volatile("s_barrier" ::: "memory");

        const _Float16* bh = (const _Float16*)lds[u & 1];
        const _Float16* bl = bh + 8192;
        f32x16 acc0 = {}, acc1 = {};
#pragma unroll
        for (int ks = 0; ks < 8; ++ks) {
            const int bo = ((ks * 2 + lh) * 64 + bo_base) * 8;
            half8 vbl = *(const half8*)(bl + bo);
            half8 vbh = *(const half8*)(bh + bo);
            acc0 = __builtin_amdgcn_mfma_f32_32x32x16_f16(Ah[0][ks], vbl, acc0, 0, 0, 0);
            acc1 = __builtin_amdgcn_mfma_f32_32x32x16_f16(Ah[1][ks], vbl, acc1, 0, 0, 0);
            acc0 = __builtin_amdgcn_mfma_f32_32x32x16_f16(Ah[0][ks], vbh, acc0, 0, 0, 0);
            acc1 = __builtin_amdgcn_mfma_f32_32x32x16_f16(Ah[1][ks], vbh, acc1, 0, 0, 0);
            acc0 = __builtin_amdgcn_mfma_f32_32x32x16_f16(Al[0][ks], vbh, acc0, 0, 0, 0);
            acc1 = __builtin_amdgcn_mfma_f32_32x32x16_f16(Al[1][ks], vbh, acc1, 0, 0, 0);
        }

        // fold dist = cnorm - 2*dot into running argmin
#pragma unroll
        for (int r = 0; r < 16; ++r) {
            float d0 = fmaf(-2.0f, acc0[r], cn0);
            float d1 = fmaf(-2.0f, acc1[r], cn0);
            if (d0 < minv[0][r]) { minv[0][r] = d0; mini[0][r] = colv; }
            if (d1 < minv[1][r]) { minv[1][r] = d1; mini[1][r] = colv; }
        }
        // all waves done reading lds[u&1] before next iter's prefetch overwrite
        asm volatile("s_barrier" ::: "memory");
    }

    // ---- reduce across the 32 l31-lanes sharing each output row ----
#pragma unroll
    for (int rt = 0; rt < 2; ++rt)
#pragma unroll
        for (int r = 0; r < 16; ++r) {
            float v = minv[rt][r];
            int ix = mini[rt][r];
#pragma unroll
            for (int off = 1; off < 32; off <<= 1) {
                float v2 = __shfl_xor(v, off);
                int i2 = __shfl_xor(ix, off);
                if (v2 < v || (v2 == v && i2 < ix)) { v = v2; ix = i2; }
            }
            if (l31 == 0) {
                // C/D row map (m74/m101): row32 = (r&3) + 8*(r>>2) + 4*lh
                int row = rg * 128 + wy * 64 + rt * 32 + 4 * lh + (r & 3) + 8 * (r >> 2);
                unsigned int uenc = __float_as_uint(v);
                uenc = (uenc & 0x80000000u) ? ~uenc : (uenc | 0x80000000u);
                u64 pk = ((u64)uenc << 13) | (u64)(unsigned)ix;
                atomicMin(&packed[row], pk);
            }
        }
}

// ---- epilogue: indices, z_q_st, counts, dw ----
__global__ __launch_bounds__(256) void k_epilogue(const float* __restrict__ z_e,
                                                  const float* __restrict__ cb,
                                                  const u64* __restrict__ packed,
                                                  float* __restrict__ out0,
                                                  float* __restrict__ out1,
                                                  float* __restrict__ counts,
                                                  float* __restrict__ dw) {
    __shared__ int idxS[64];
    const int tid = threadIdx.x;
    const int n0 = blockIdx.x * 64;
    const int bb = n0 >> 10, p0 = n0 & 1023;

    if (tid < 64) {
        int ix = (int)(packed[n0 + tid] & 0x1FFFull);
        idxS[tid] = ix;
        out1[n0 + tid] = (float)ix;
        atomicAdd(&counts[ix], 1.0f);
    }
    __syncthreads();

    const float* zb = z_e + (size_t)bb * (D * HW) + p0;
    float* ob = out0 + (size_t)bb * (D * HW) + p0;

    for (int i = tid; i < 64 * D; i += 256) {
        int d = i >> 6, r = i & 63;
        float z = zb[(size_t)d * HW + r];
        float c = cb[(size_t)idxS[r] * D + d];
        ob[(size_t)d * HW + r] = z + (c - z);
    }
    for (int i = tid; i < 64 * D; i += 256) {
        int r = i >> 7, d = i & 127;
        atomicAdd(&dw[(size_t)idxS[r] * D + d], zb[(size_t)d * HW + r]);
    }
}

__global__ __launch_bounds__(256) void k_final(const float* __restrict__ ema_count,
                                               const float* __restrict__ ema_weight,
                                               float* __restrict__ out2,
                                               float* __restrict__ out3,
                                               float* __restrict__ out4) {
    int gid = blockIdx.x * 256 + threadIdx.x;   // over K*D
    int k = gid >> 7, d = gid & 127;
    float cnt_raw = out3[k];
    float dw_raw = out4[gid];
    __syncthreads();
    float nc = 0.99f * ema_count[k] + 0.01f * cnt_raw;
    float nw = 0.99f * ema_weight[gid] + 0.01f * dw_raw;
    out4[gid] = nw;
    out2[gid] = nw / fmaxf(nc, 1.0f);
    if (d == 0) out3[k] = nc;
}

extern "C" void kernel_launch(void* const* d_in, const int* in_sizes, int n_in,
                              void* d_out, int out_size, void* d_ws, size_t ws_size,
                              hipStream_t stream) {
    const float* z_e        = (const float*)d_in[0];
    const float* cb         = (const float*)d_in[1];
    const float* ema_count  = (const float*)d_in[2];
    const float* ema_weight = (const float*)d_in[3];
    float* out = (float*)d_out;

    float* cnorm = (float*)d_ws;                                   // K floats
    u64* packed = (u64*)((char*)d_ws + K * 4);                     // NROWS u64

    // fp16-split B lives in out2 (4 MB, rewritten by k_final later):
    u16* Bg = (u16*)(out + OUT2);                                  // 128 units x 32 KiB

    k_prep_cb    <<<K / 16,        256, 0, stream>>>(cb, Bg, cnorm, packed,
                                                     out + OUT3, out + OUT4);
    k_argmin_mfma<<<512,           256, 0, stream>>>(z_e, Bg, cnorm, packed);
    k_epilogue   <<<NROWS / 64,    256, 0, stream>>>(z_e, cb, packed,
                                                     out + OUT0, out + OUT1,
                                                     out + OUT3, out + OUT4);
    k_final      <<<(K * D) / 256, 256, 0, stream>>>(ema_count, ema_weight,
                                                     out + OUT2, out + OUT3, out + OUT4);
}